// Round 1
// baseline (140.676 us; speedup 1.0000x reference)
//
#include <hip/hip_runtime.h>
#include <hip/hip_bf16.h>
#include <stdint.h>

#define T_SEQ 4096
#define C_EMB 768
#define C3    2304
#define CQK   1536
#define NH    12
#define HD    64
#define CH    16        // k-tiles (of 64) per attention chunk-block
#define NSLOT 1728      // 12 heads * 144 multi-chunk partial slots

typedef __attribute__((ext_vector_type(8))) short short8;
typedef __attribute__((ext_vector_type(4))) short short4v;
typedef __attribute__((ext_vector_type(4))) float f32x4;

__device__ __forceinline__ short f2bf(float f) {
  __bf16 h = (__bf16)f;
  return __builtin_bit_cast(short, h);
}

__device__ __forceinline__ void gload_lds16(const void* g, void* l) {
  __builtin_amdgcn_global_load_lds((const __attribute__((address_space(1))) void*)g,
                                   (__attribute__((address_space(3))) void*)l, 16, 0, 0);
}

// ---------------- prep kernels ----------------
__global__ __launch_bounds__(256)
void cvt_kernel(const float* __restrict__ in, short* __restrict__ out, int n4) {
  int i = blockIdx.x * 256 + threadIdx.x;
  if (i < n4) {
    float4 v = ((const float4*)in)[i];
    short4v s = { f2bf(v.x), f2bf(v.y), f2bf(v.z), f2bf(v.w) };
    ((short4v*)out)[i] = s;
  }
}

// W [K][N] fp32 -> WT [N][K] bf16
__global__ __launch_bounds__(256)
void transpose_cvt_kernel(const float* __restrict__ W, short* __restrict__ WT,
                          int K, int N) {
  __shared__ float ts[32][33];
  const int r0 = blockIdx.y * 32, c0 = blockIdx.x * 32;
  const int tid = threadIdx.x;
  {
    int rr = tid >> 3, c4 = (tid & 7) * 4;
    float4 v = *(const float4*)(W + (size_t)(r0 + rr) * N + c0 + c4);
    ts[rr][c4 + 0] = v.x; ts[rr][c4 + 1] = v.y;
    ts[rr][c4 + 2] = v.z; ts[rr][c4 + 3] = v.w;
  }
  __syncthreads();
  {
    int nr = tid >> 3, k4 = (tid & 7) * 4;
    short4v s = { f2bf(ts[k4 + 0][nr]), f2bf(ts[k4 + 1][nr]),
                  f2bf(ts[k4 + 2][nr]), f2bf(ts[k4 + 3][nr]) };
    *(short4v*)(WT + (size_t)(c0 + nr) * K + r0 + k4) = s;
  }
}

// ---------------- GEMM: C = A(bf16 MxK) @ Bt(bf16 NxK)^T + bias ----------------
// SPLIT_V: N-blocks with col0>=1536 write transposed into Vt[d][t], with the
// k-permutation p(t64) = (t&32) + ((t&12)<<1) + ((t&16)>>2) + (t&3) inside each
// 64-wide t-tile, so attention's PV can consume P directly from registers.
template<int BN, bool SPLIT_V, bool OUT_F32>
__global__ __launch_bounds__(256)
void gemm_kernel(const short* __restrict__ A, const short* __restrict__ Bt,
                 const float* __restrict__ bias, void* __restrict__ Cp,
                 short* __restrict__ Vt, int N, int K) {
  constexpr int MF = (BN == 128) ? 4 : 2;
  __shared__ short As[128 * 32];
  __shared__ short Bs[BN * 32];
  const int row0 = blockIdx.y * 128, col0 = blockIdx.x * BN;
  const int tid = threadIdx.x, lane = tid & 63, wave = tid >> 6;
  const int lg = lane >> 4, lr = lane & 15;
  const int wr = (BN == 128) ? ((wave >> 1) * 64) : (wave * 32);
  const int wc = (BN == 128) ? ((wave & 1) * 64) : 0;

  f32x4 acc[MF][4];
  #pragma unroll
  for (int m_ = 0; m_ < MF; ++m_)
    #pragma unroll
    for (int n_ = 0; n_ < 4; ++n_) acc[m_][n_] = (f32x4){0.f, 0.f, 0.f, 0.f};

  const int srow = wave * 16 + (lane >> 2);
  const int scol = (lane & 3) * 8;

  for (int kt = 0; kt < K; kt += 32) {
    __syncthreads();
    #pragma unroll
    for (int c = 0; c < 2; ++c)
      gload_lds16(A + (size_t)(row0 + c * 64 + srow) * K + kt + scol,
                  As + c * 2048 + wave * 512);
    #pragma unroll
    for (int c = 0; c < BN / 64; ++c)
      gload_lds16(Bt + (size_t)(col0 + c * 64 + srow) * K + kt + scol,
                  Bs + c * 2048 + wave * 512);
    __syncthreads();

    short8 a[MF], b[4];
    #pragma unroll
    for (int m_ = 0; m_ < MF; ++m_)
      a[m_] = *(const short8*)&As[(wr + m_ * 16 + lr) * 32 + lg * 8];
    #pragma unroll
    for (int n_ = 0; n_ < 4; ++n_)
      b[n_] = *(const short8*)&Bs[(wc + n_ * 16 + lr) * 32 + lg * 8];
    #pragma unroll
    for (int m_ = 0; m_ < MF; ++m_)
      #pragma unroll
      for (int n_ = 0; n_ < 4; ++n_)
        acc[m_][n_] = __builtin_amdgcn_mfma_f32_16x16x32_bf16(a[m_], b[n_], acc[m_][n_], 0, 0, 0);
  }

  const bool isV = SPLIT_V && (col0 >= CQK);
  #pragma unroll
  for (int n_ = 0; n_ < 4; ++n_) {
    const int col = col0 + wc + n_ * 16 + lr;
    const float bv = bias[col];
    #pragma unroll
    for (int m_ = 0; m_ < MF; ++m_) {
      const int rbase = row0 + wr + m_ * 16 + lg * 4;
      if constexpr (OUT_F32) {
        #pragma unroll
        for (int r = 0; r < 4; ++r)
          ((float*)Cp)[(size_t)(rbase + r) * N + col] = acc[m_][n_][r] + bv;
      } else {
        if (!isV) {
          const int nout = SPLIT_V ? CQK : N;
          #pragma unroll
          for (int r = 0; r < 4; ++r)
            ((short*)Cp)[(size_t)(rbase + r) * nout + col] = f2bf(acc[m_][n_][r] + bv);
        } else {
          short4v p = { f2bf(acc[m_][n_][0] + bv), f2bf(acc[m_][n_][1] + bv),
                        f2bf(acc[m_][n_][2] + bv), f2bf(acc[m_][n_][3] + bv) };
          const int t64 = rbase & 63;   // 4-aligned; permute within 64-tile
          const int p64 = (t64 & 32) + ((t64 & 12) << 1) + ((t64 & 16) >> 2);
          *(short4v*)(Vt + (size_t)(col - CQK) * T_SEQ + (rbase & ~63) + p64) = p;
        }
      }
    }
  }
}

// ---------------- flash attention (causal), chunked split-K across blocks ----
// Grid = 1920 blocks: one per (head, q-tile, k-chunk of CH=16 tiles). Within a
// block: 8 waves = 2 k-parity streams x 4 qslots (unchanged verified inner
// loop). Blocks with qt < CH (single chunk) normalize and write bf16 directly;
// multi-chunk blocks write unnormalized f32 partial O + per-row (m,l) to
// workspace, combined by merge_kernel. This caps the serial critical path at
// 8 iterations (was 32 for the ntiles=64 diagonal blocks) and balances the
// causal-mask work imbalance across the grid.
// LDS = 4 x [64][72] bf16 = 36 KB -> 4 blocks/CU (144 KB), 32 waves/CU.
// NOTE: __launch_bounds__ 2nd arg behaves as min BLOCKS/CU here (R5 evidence:
// (512,6) => 48 waves/CU => 40-VGPR cap => spills => WRITE_SIZE 6->42 MB).
__global__ __launch_bounds__(512, 4)
void attn_kernel(const short* __restrict__ qk, const short* __restrict__ Vt,
                 short* __restrict__ out, float* __restrict__ pO,
                 float* __restrict__ pML) {
  __shared__ short smem[18432];   // Ke|Ko|Ve|Vo, each [64][72]
  const int bd = blockIdx.x;
  const int h = bd % NH;
  const int ii = 159 - bd / NH;   // descending qt: full 16-tile chunks first
  int qt, ck;
  if (ii < 16)      { qt = ii;                 ck = 0; }
  else if (ii < 48) { qt = 16 + (ii - 16) / 2; ck = (ii - 16) % 2; }
  else if (ii < 96) { qt = 32 + (ii - 48) / 3; ck = (ii - 48) % 3; }
  else              { qt = 48 + (ii - 96) / 4; ck = (ii - 96) % 4; }
  const int q0 = qt * 64;
  const int ntiles = qt + 1;          // causal: tiles 0..qt
  const int t0 = ck * CH;             // first tile of this chunk
  const int rem = ntiles - t0;
  const int nloc = rem < CH ? rem : CH;

  const int tid = threadIdx.x, lane = tid & 63, wave = tid >> 6;
  const int st = wave >> 2, qslot = wave & 3;
  const int lg = lane >> 4, lr = lane & 15;
  const int q = q0 + qslot * 16 + lr;
  const float SC = 0.18033688011f;   // (1/8) * log2(e)

  short (*Ks)[72] = (short(*)[72])(smem + st * 4608);
  short (*Vs)[72] = (short(*)[72])(smem + 9216 + st * 4608);

  short8 qf[2];
  qf[0] = *(const short8*)(qk + (size_t)q * CQK + h * HD + lg * 8);
  qf[1] = *(const short8*)(qk + (size_t)q * CQK + h * HD + 32 + lg * 8);

  float mrun = -1e30f, lrun = 0.f;
  f32x4 o[4];
  #pragma unroll
  for (int d = 0; d < 4; ++d) o[d] = (f32x4){0.f, 0.f, 0.f, 0.f};

  const int srow = qslot * 16 + (lane >> 3);   // + p*8 covers 16 rows per wave
  const int scol = (lane & 7) * 8;
  const short* Kg = qk + C_EMB + h * HD;
  const short* Vg = Vt + (size_t)(h * HD) * T_SEQ;

  const int nO = nloc >> 1, nE = nloc - nO;
  const int nMine = st ? nO : nE;

  if (nMine > 0) {   // prologue: stage my stream's first tile
    const int kt = (t0 + st) * 64;
    #pragma unroll
    for (int p = 0; p < 2; ++p) {
      const int r = srow + 8 * p;
      *(short8*)&Ks[r][scol] = *(const short8*)(Kg + (size_t)(kt + r) * CQK + scol);
      *(short8*)&Vs[r][scol] = *(const short8*)(Vg + (size_t)r * T_SEQ + kt + scol);
    }
  }
  __syncthreads();

  for (int tt = 0; tt < nE; ++tt) {
    const bool haveNext = (tt + 1 < nMine);
    short8 kr[2], vr[2];
    if (haveNext) {   // T14: issue next-tile loads before compute
      const int kt = (t0 + 2 * (tt + 1) + st) * 64;
      #pragma unroll
      for (int p = 0; p < 2; ++p) {
        const int r = srow + 8 * p;
        kr[p] = *(const short8*)(Kg + (size_t)(kt + r) * CQK + scol);
        vr[p] = *(const short8*)(Vg + (size_t)r * T_SEQ + kt + scol);
      }
    }

    if (tt < nMine) {
      const int tl = t0 + 2 * tt + st;   // my global tile index
      // S^T[k][q] = K Q^T (raw domain)
      f32x4 s[4];
      __builtin_amdgcn_s_setprio(1);
      #pragma unroll
      for (int n = 0; n < 4; ++n) {
        f32x4 cc = (f32x4){0.f, 0.f, 0.f, 0.f};
        #pragma unroll
        for (int ks = 0; ks < 2; ++ks) {
          short8 kb = *(const short8*)&Ks[n * 16 + lr][ks * 32 + lg * 8];
          cc = __builtin_amdgcn_mfma_f32_16x16x32_bf16(kb, qf[ks], cc, 0, 0, 0);
        }
        s[n] = cc;
      }
      __builtin_amdgcn_s_setprio(0);

      if (tl == ntiles - 1) {   // diagonal tile: mask k_local > q_local
        #pragma unroll
        for (int n = 0; n < 4; ++n)
          #pragma unroll
          for (int r = 0; r < 4; ++r)
            if (n * 16 + lg * 4 + r > qslot * 16 + lr) s[n][r] = -1e30f;
      }

      float pmax = s[0][0];
      #pragma unroll
      for (int n = 0; n < 4; ++n)
        #pragma unroll
        for (int r = 0; r < 4; ++r) pmax = fmaxf(pmax, s[n][r]);
      pmax = fmaxf(pmax, __shfl_xor(pmax, 16));
      pmax = fmaxf(pmax, __shfl_xor(pmax, 32));

      if (!__all(pmax <= mrun + 44.0f)) {   // defer-max (raw 44 ~= 2^8 bound)
        const float mn = fmaxf(mrun, pmax);
        const float al = exp2f((mrun - mn) * SC);
        lrun *= al;
        #pragma unroll
        for (int d = 0; d < 4; ++d) o[d] *= al;
        mrun = mn;
      }
      const float msc = mrun * SC;

      float psum = 0.f;
      #pragma unroll
      for (int n = 0; n < 4; ++n)
        #pragma unroll
        for (int r = 0; r < 4; ++r) {
          float p = exp2f(fmaf(s[n][r], SC, -msc));
          s[n][r] = p;
          psum += p;
        }
      psum += __shfl_xor(psum, 16);
      psum += __shfl_xor(psum, 32);
      lrun += psum;

      // O^T += V^T P^T ; P B-fragment built in-register (kk bijection)
      __builtin_amdgcn_s_setprio(1);
      #pragma unroll
      for (int ks = 0; ks < 2; ++ks) {
        short8 pb = { f2bf(s[2 * ks][0]),     f2bf(s[2 * ks][1]),
                      f2bf(s[2 * ks][2]),     f2bf(s[2 * ks][3]),
                      f2bf(s[2 * ks + 1][0]), f2bf(s[2 * ks + 1][1]),
                      f2bf(s[2 * ks + 1][2]), f2bf(s[2 * ks + 1][3]) };
        #pragma unroll
        for (int d = 0; d < 4; ++d) {
          short8 av = *(const short8*)&Vs[d * 16 + lr][ks * 32 + lg * 8];
          o[d] = __builtin_amdgcn_mfma_f32_16x16x32_bf16(av, pb, o[d], 0, 0, 0);
        }
      }
      __builtin_amdgcn_s_setprio(0);
    }

    __syncthreads();              // all waves done reading K/V buffers
    if (haveNext) {
      #pragma unroll
      for (int p = 0; p < 2; ++p) {
        const int r = srow + 8 * p;
        *(short8*)&Ks[r][scol] = kr[p];
        *(short8*)&Vs[r][scol] = vr[p];
      }
    }
    __syncthreads();              // buffers ready for next iter
  }

  // -------- merge even/odd stream partials (reuse K/V LDS) --------
  float* mo = (float*)smem;                        // [64][68] f32
  float* ml = (float*)((char*)smem + 17408);       // [64][2]  f32
  if (st == 1) {
    const int row = qslot * 16 + lr;
    #pragma unroll
    for (int d = 0; d < 4; ++d)
      *(f32x4*)&mo[row * 68 + d * 16 + lg * 4] = o[d];
    if (lg == 0) {
      ml[row * 2 + 0] = mrun;
      ml[row * 2 + 1] = lrun;
    }
  }
  __syncthreads();
  if (st == 0) {
    const int row = qslot * 16 + lr;
    const float mb = ml[row * 2 + 0], lb = ml[row * 2 + 1];
    const float M = fmaxf(mrun, mb);
    const float aa = exp2f((mrun - M) * SC);
    const float ab = exp2f((mb - M) * SC);
    const float lmerged = lrun * aa + lb * ab;
    if (qt < CH) {
      // single chunk: normalize and write bf16 directly
      const float linv = 1.f / lmerged;
      #pragma unroll
      for (int d = 0; d < 4; ++d) {
        f32x4 ob = *(const f32x4*)&mo[row * 68 + d * 16 + lg * 4];
        short4v ov;
        #pragma unroll
        for (int r = 0; r < 4; ++r)
          ov[r] = f2bf((o[d][r] * aa + ob[r] * ab) * linv);
        *(short4v*)(out + (size_t)q * C_EMB + h * HD + d * 16 + lg * 4) = ov;
      }
    } else {
      // multi-chunk: write unnormalized f32 partial with base M
      const int sbase = (qt < 32) ? 2 * (qt - 16)
                      : (qt < 48) ? 32 + 3 * (qt - 32)
                                  : 80 + 4 * (qt - 48);
      const int slot = h * 144 + sbase + ck;
      float* po = pO + (size_t)slot * 4096 + row * 64;
      #pragma unroll
      for (int d = 0; d < 4; ++d) {
        f32x4 ob = *(const f32x4*)&mo[row * 68 + d * 16 + lg * 4];
        f32x4 v;
        #pragma unroll
        for (int r = 0; r < 4; ++r) v[r] = o[d][r] * aa + ob[r] * ab;
        *(f32x4*)&po[d * 16 + lg * 4] = v;
      }
      if (lg == 0) {
        pML[(size_t)slot * 128 + row * 2 + 0] = M;
        pML[(size_t)slot * 128 + row * 2 + 1] = lmerged;
      }
    }
  }
}

// ---------------- merge partial chunks: out = sum_i a_i O_i / sum_i a_i l_i --
__global__ __launch_bounds__(256)
void merge_kernel(const float* __restrict__ pO, const float* __restrict__ pML,
                  short* __restrict__ out) {
  const int bd = blockIdx.x;          // 576 = 12 heads * 48 multi-chunk q-tiles
  const int h = bd % NH;
  const int qt = 16 + bd / NH;        // 16..63
  const int nc = qt / CH + 1;         // 2..4 chunks
  const int sbase = (qt < 32) ? 2 * (qt - 16)
                  : (qt < 48) ? 32 + 3 * (qt - 32)
                              : 80 + 4 * (qt - 48);
  const int slot0 = h * 144 + sbase;
  const int tid = threadIdx.x;
  const int q = tid >> 2, dc = (tid & 3) << 4;   // q row 0..63, d chunk of 16
  const float SC = 0.18033688011f;

  float mi[4], li[4];
  float M = -1e30f;
  #pragma unroll
  for (int i = 0; i < 4; ++i)
    if (i < nc) {
      mi[i] = pML[(size_t)(slot0 + i) * 128 + q * 2 + 0];
      li[i] = pML[(size_t)(slot0 + i) * 128 + q * 2 + 1];
      M = fmaxf(M, mi[i]);
    }

  f32x4 O[4];
  #pragma unroll
  for (int d4 = 0; d4 < 4; ++d4) O[d4] = (f32x4){0.f, 0.f, 0.f, 0.f};
  float L = 0.f;
  #pragma unroll
  for (int i = 0; i < 4; ++i)
    if (i < nc) {
      const float a = exp2f((mi[i] - M) * SC);
      L = fmaf(li[i], a, L);
      const float* po = pO + (size_t)(slot0 + i) * 4096 + q * 64 + dc;
      #pragma unroll
      for (int d4 = 0; d4 < 4; ++d4) {
        f32x4 v = *(const f32x4*)(po + d4 * 4);
        #pragma unroll
        for (int r = 0; r < 4; ++r) O[d4][r] = fmaf(v[r], a, O[d4][r]);
      }
    }

  const float linv = 1.f / L;
  #pragma unroll
  for (int d4 = 0; d4 < 4; ++d4) {
    short4v ov;
    #pragma unroll
    for (int r = 0; r < 4; ++r) ov[r] = f2bf(O[d4][r] * linv);
    *(short4v*)(out + (size_t)(qt * 64 + q) * C_EMB + h * HD + dc + d4 * 4) = ov;
  }
}

extern "C" void kernel_launch(void* const* d_in, const int* in_sizes, int n_in,
                              void* d_out, int out_size, void* d_ws, size_t ws_size,
                              hipStream_t stream) {
  const float* x    = (const float*)d_in[0];
  const float* Wqkv = (const float*)d_in[1];
  const float* bqkv = (const float*)d_in[2];
  const float* Wout = (const float*)d_in[3];
  const float* bout = (const float*)d_in[4];

  short* xb    = (short*)d_ws;                        // [4096][768]  (later: attn out)
  short* WqkvT = xb    + (size_t)T_SEQ * C_EMB;       // [2304][768]
  short* WoutT = WqkvT + (size_t)C3 * C_EMB;          // [768][768]
  short* qk    = WoutT + (size_t)C_EMB * C_EMB;       // [4096][1536]  (Q|K)
  short* Vt    = qk    + (size_t)T_SEQ * CQK;         // [768][4096]   (V^T, k-permuted)
  float* pO    = (float*)(Vt + (size_t)C_EMB * T_SEQ); // [1728][64][64] f32 partials
  float* pML   = pO + (size_t)NSLOT * 4096;            // [1728][64][2]  f32 (m,l)

  cvt_kernel<<<(T_SEQ * C_EMB / 4) / 256, 256, 0, stream>>>(x, xb, T_SEQ * C_EMB / 4);
  transpose_cvt_kernel<<<dim3(C3 / 32, C_EMB / 32), 256, 0, stream>>>(Wqkv, WqkvT, C_EMB, C3);
  transpose_cvt_kernel<<<dim3(C_EMB / 32, C_EMB / 32), 256, 0, stream>>>(Wout, WoutT, C_EMB, C_EMB);

  gemm_kernel<128, true, false><<<dim3(C3 / 128, T_SEQ / 128), 256, 0, stream>>>(
      xb, WqkvT, bqkv, qk, Vt, C3, C_EMB);

  attn_kernel<<<dim3(NH * 160), 512, 0, stream>>>(qk, Vt, xb, pO, pML);
  merge_kernel<<<dim3(NH * 48), 256, 0, stream>>>(pO, pML, xb);

  gemm_kernel<64, false, true><<<dim3(C_EMB / 64, T_SEQ / 128), 256, 0, stream>>>(
      xb, WoutT, bout, d_out, nullptr, C_EMB, C_EMB);
}